// Round 4
// baseline (91.000 us; speedup 1.0000x reference)
//
#include <hip/hip_runtime.h>

// DGraFormer graph-propagation, algebraically collapsed to 6 matvecs of
// A=adj[b,s,:,:] (64x64) per (b,s):
//   out[n] = sum_k P'_k y_k[n] + sum_k Q_k u_k[n] + (Q_0 + b_mlp)
//   y_k = (0.95 A^T)^k x[b,:,s],  u_k = (0.95 A^T)^k 1.
// HBM-bound: one pass over adj (176 MB), floor ~29 us.
//
// Round-4 structure: async 2-phase pipeline (T3-minimum), full occupancy.
//  - block = 8 waves = one (b, s4) tile; 4 tasks (s values) sequential.
//  - A staged to LDS double-buffer via inline-asm global_load_lds_dwordx4;
//    wave w stages rows 8w..8w+7 = its own compute rows -> per-wave counted
//    vmcnt(2) gating, no staging barrier, loads stay in flight across
//    __syncthreads (asm loads invisible to compiler's waitcnt pass).
//  - 8-way row-split matvec, partial exchange via part[8][64] LDS, 2 barriers/k.
//  - VGPR ~50 target; __launch_bounds__(512,8) -> 32 waves/CU.

#define BB 32
#define NN 64
#define SS 336
#define DD 32
#define BETA 0.05f
#define OMB 0.95f

#define VMWAIT2() asm volatile("s_waitcnt vmcnt(2)" ::: "memory")
#define VMWAIT0() asm volatile("s_waitcnt vmcnt(0)" ::: "memory")

// async 1 KB global->LDS: 64 lanes x 16 B. LDS dest = m0 + lane*16 (HW),
// global src = gsrc (per-lane, must match lane*16 stride). m0 restored to -1
// (gfx9 DS bounds descriptor) in the same asm block.
__device__ __forceinline__ void glds_1kb(const float* gsrc, unsigned lds_byte_off) {
    unsigned m0v = __builtin_amdgcn_readfirstlane(lds_byte_off);
    asm volatile("s_mov_b32 m0, %0\n\t"
                 "global_load_lds_dwordx4 %1, off\n\t"
                 "s_mov_b32 m0, -1"
                 :: "s"(m0v), "v"(gsrc) : "memory");
}

__global__ __launch_bounds__(512, 8) void dgra_pipe_kernel(
    const float* __restrict__ x, const float* __restrict__ adj,
    const float* __restrict__ w_start, const float* __restrict__ b_start,
    const float* __restrict__ w_mlp, const float* __restrict__ b_mlp,
    float* __restrict__ out)
{
    const int tid  = threadIdx.x;
    const int lane = tid & 63;
    const int w    = tid >> 6;           // 0..7: row block 8w..8w+7
    const int b    = blockIdx.x / (SS / 4);
    const int s4   = blockIdx.x % (SS / 4);
    const int s0   = s4 * 4;

    __shared__ __align__(16) float  Abuf[2][NN * NN];   // 32 KB double buffer
    __shared__ __align__(16) float2 part[8][NN];        // 4 KB partial exchange
    __shared__ __align__(16) float2 yu[NN];             // (y,u) broadcast

    const float* Abase = adj + (size_t)(b * SS + s0) * (NN * NN);

    // x for n=lane at the 4 consecutive s (16B-aligned: 1344 and 16*s4)
    const float4 xq = *reinterpret_cast<const float4*>(&x[(size_t)(b * NN + lane) * SS + s0]);
    const float xj[4] = {xq.x, xq.y, xq.z, xq.w};

    const unsigned buf0 = (unsigned)(uintptr_t)(&Abuf[0][0]) + (unsigned)(w * 2048);
    const unsigned buf1 = (unsigned)(uintptr_t)(&Abuf[1][0]) + (unsigned)(w * 2048);

    // DMA tile 0 (this wave's 8 rows = 2 KB = 2 instrs)
    {
        const float* g = Abase + w * 512 + lane * 4;
        glds_1kb(g,       buf0);
        glds_1kb(g + 256, buf0 + 1024);
    }

    // ---- MLP fold (per-wave butterfly; round-3 proven numerics) ----
    const int  c2 = lane & 31;
    const int  hi = lane >> 5;
    const float wd  = w_start[c2];
    const float bd  = b_start[c2];
    const float m0f = w_mlp[(2 * hi + 0) * DD + c2];
    const float m1f = w_mlp[(2 * hi + 1) * DD + c2];
    float p0 = wd * m0f, q0 = bd * m0f, r0 = m0f;
    float p1 = wd * m1f, q1 = bd * m1f, r1 = m1f;
#pragma unroll
    for (int mask = 1; mask <= 16; mask <<= 1) {
        p0 += __shfl_xor(p0, mask, 64);  q0 += __shfl_xor(q0, mask, 64);  r0 += __shfl_xor(r0, mask, 64);
        p1 += __shfl_xor(p1, mask, 64);  q1 += __shfl_xor(q1, mask, 64);  r1 += __shfl_xor(r1, mask, 64);
    }
    const float po0 = __shfl_xor(p0, 32, 64), qo0 = __shfl_xor(q0, 32, 64), ro0 = __shfl_xor(r0, 32, 64);
    const float po1 = __shfl_xor(p1, 32, 64), qo1 = __shfl_xor(q1, 32, 64), ro1 = __shfl_xor(r1, 32, 64);
    const bool lo = (hi == 0);
    const float P0 = lo ? p0  : po0, P1 = lo ? p1  : po1, P2 = lo ? po0 : p0, P3 = lo ? po1 : p1;
    const float Q0 = lo ? q0  : qo0, Q1 = lo ? q1  : qo1, Q2 = lo ? qo0 : q0, Q3 = lo ? qo1 : q1;
    const float R1 = lo ? r1  : ro1, R2 = lo ? ro0 : r0,  R3 = lo ? ro1 : r1;
    const float PpA[4] = {P0 + BETA * (R1 + R2 + R3), P1 + BETA * (R2 + R3), P2 + BETA * R3, P3};
    const float QA[4]  = {Q0, Q1, Q2, Q3};
    const float c0f = Q0 + b_mlp[0];

    if (w == 0) yu[lane] = make_float2(xj[0], 1.0f);
    __syncthreads();

    // Force the xq wait here (compiler-tracked vmcnt drains to 0 now, while
    // only DMA0 is in flight) so no vmcnt(0) lands inside the pipelined loop.
    asm volatile("" :: "v"(xq.x), "v"(xq.y), "v"(xq.z), "v"(xq.w));

    float acc[4];

#pragma unroll
    for (int j = 0; j < 4; ++j) {
        // prefetch next tile into the other buffer, then wait only for tile j
        if (j < 3) {
            const float* g = Abase + (j + 1) * 4096 + w * 512 + lane * 4;
            const unsigned dst = ((j + 1) & 1) ? buf1 : buf0;
            glds_1kb(g,       dst);
            glds_1kb(g + 256, dst + 1024);
            VMWAIT2();          // 2 newest (next tile) stay in flight
        } else {
            VMWAIT0();
        }

        const float* Ab = &Abuf[j & 1][0];
        float av[8];
#pragma unroll
        for (int i = 0; i < 8; ++i)
            av[i] = Ab[(8 * w + i) * NN + lane];   // own staged region

        acc[j] = fmaf(PpA[0], xj[j], c0f);

#pragma unroll
        for (int k = 1; k <= 3; ++k) {
            float py = 0.f, pu = 0.f;
#pragma unroll
            for (int i = 0; i < 8; ++i) {
                const float2 t = yu[8 * w + i];    // uniform addr -> broadcast
                py = fmaf(av[i], t.x, py);
                pu = fmaf(av[i], t.y, pu);
            }
            part[w][lane] = make_float2(py, pu);
            __syncthreads();
            float ys = 0.f, us = 0.f;
#pragma unroll
            for (int p = 0; p < 8; ++p) {          // redundant combine, all waves
                const float2 t = part[p][lane];
                ys += t.x; us += t.y;
            }
            ys *= OMB; us *= OMB;
            acc[j] = fmaf(PpA[k], ys, fmaf(QA[k], us, acc[j]));
            if (w == 0) {
                if (k < 3)      yu[lane] = make_float2(ys, us);
                else if (j < 3) yu[lane] = make_float2(xj[j + 1], 1.0f);  // next task init
            }
            __syncthreads();
        }
    }

    if (w == 0) {
        float4 o; o.x = acc[0]; o.y = acc[1]; o.z = acc[2]; o.w = acc[3];
        *reinterpret_cast<float4*>(&out[(size_t)(b * NN + lane) * SS + s0]) = o;
    }
}

extern "C" void kernel_launch(void* const* d_in, const int* in_sizes, int n_in,
                              void* d_out, int out_size, void* d_ws, size_t ws_size,
                              hipStream_t stream) {
    const float* x       = (const float*)d_in[0];
    const float* adj     = (const float*)d_in[1];
    const float* w_start = (const float*)d_in[2];
    const float* b_start = (const float*)d_in[3];
    const float* w_mlp   = (const float*)d_in[4];
    const float* b_mlp   = (const float*)d_in[5];
    float* out = (float*)d_out;

    const int grid = BB * (SS / 4);      // 2688 blocks x 512 thr (8 waves)
    dgra_pipe_kernel<<<grid, 512, 0, stream>>>(x, adj, w_start, b_start, w_mlp, b_mlp, out);
}

// Round 5
// 41.715 us; speedup vs baseline: 2.1815x; 2.1815x over previous
//
#include <hip/hip_runtime.h>

// DGraFormer graph-propagation, algebraically collapsed to 6 matvecs of
// A=adj[b,s,:,:] (64x64) per (b,s):
//   out[n] = sum_k P'_k y_k[n] + sum_k Q_k u_k[n] + (Q_0 + b_mlp)
//   y_k = (0.95 A^T)^k x[b,:,s],  u_k = (0.95 A^T)^k 1.
// HBM/L3-bound: one pass over adj (176 MB; ~35% L3-resident on replays).
//
// Round-5: round-3's self-contained-wave matvec + register double-buffer
// pipelined over 4 s-values per wave. 1 wave per 64-thr block; NO
// __launch_bounds__ min-waves (rounds 2+4 proved forced VGPR targets spill,
// 3-4x regressions), NO cross-wave barriers, NO inline-asm DMA (round-4
// regression). Compiler emits counted vmcnt(32) so every wave keeps its
// next 16 KB A-tile in flight during compute -> VMEM duty cycle ~100%.

#define BB 32
#define NN 64
#define SS 336
#define DD 32
#define BETA 0.05f
#define OMB 0.95f

#define WAITLDS() __asm__ volatile("s_waitcnt lgkmcnt(0)" ::: "memory")

__global__ __launch_bounds__(64) void dgra_pipe2_kernel(
    const float* __restrict__ x, const float* __restrict__ adj,
    const float* __restrict__ w_start, const float* __restrict__ b_start,
    const float* __restrict__ w_mlp, const float* __restrict__ b_mlp,
    float* __restrict__ out)
{
    const int lane = threadIdx.x;        // one wave per block
    const int b    = blockIdx.x / (SS / 4);
    const int s4   = blockIdx.x % (SS / 4);
    const int s0   = s4 * 4;
    const int c    = lane & 31;          // column pair: cols 2c, 2c+1
    const int hi   = lane >> 5;          // row parity

    // small loads FIRST so their waits don't drain the A-tile queue
    const float wd  = w_start[c];
    const float bd  = b_start[c];
    const float m0f = w_mlp[(2 * hi + 0) * DD + c];
    const float m1f = w_mlp[(2 * hi + 1) * DD + c];
    const float bm  = b_mlp[0];

    const float* Ab = adj + (size_t)(b * SS + s0) * (NN * NN);

    // A-tile register double buffer: av*[i] = {A[2i+hi][2c], A[2i+hi][2c+1]}
    float2 avA[32], avB[32];
#pragma unroll
    for (int i = 0; i < 32; ++i)
        avA[i] = *reinterpret_cast<const float2*>(Ab + (2 * i + hi) * NN + 2 * c);

    const float4 xq = *reinterpret_cast<const float4*>(&x[(size_t)(b * NN + lane) * SS + s0]);
    const float xj[4] = {xq.x, xq.y, xq.z, xq.w};

    // ---- lane-parallel MLP fold (round-3 proven numerics) ----
    float p0 = wd * m0f, q0 = bd * m0f, r0 = m0f;
    float p1 = wd * m1f, q1 = bd * m1f, r1 = m1f;
#pragma unroll
    for (int mask = 1; mask <= 16; mask <<= 1) {
        p0 += __shfl_xor(p0, mask, 64);  q0 += __shfl_xor(q0, mask, 64);  r0 += __shfl_xor(r0, mask, 64);
        p1 += __shfl_xor(p1, mask, 64);  q1 += __shfl_xor(q1, mask, 64);  r1 += __shfl_xor(r1, mask, 64);
    }
    const float po0 = __shfl_xor(p0, 32, 64), qo0 = __shfl_xor(q0, 32, 64), ro0 = __shfl_xor(r0, 32, 64);
    const float po1 = __shfl_xor(p1, 32, 64), qo1 = __shfl_xor(q1, 32, 64), ro1 = __shfl_xor(r1, 32, 64);
    const bool lo = (hi == 0);
    const float P0 = lo ? p0  : po0, P1 = lo ? p1  : po1, P2 = lo ? po0 : p0, P3 = lo ? po1 : p1;
    const float Q0 = lo ? q0  : qo0, Q1 = lo ? q1  : qo1, Q2 = lo ? qo0 : q0, Q3 = lo ? qo1 : q1;
    const float R1 = lo ? r1  : ro1, R2 = lo ? ro0 : r0,  R3 = lo ? ro1 : r1;
    const float PpA[4] = {P0 + BETA * (R1 + R2 + R3), P1 + BETA * (R2 + R3), P2 + BETA * R3, P3};
    const float QA[4]  = {Q0, Q1, Q2, Q3};
    const float c0f = Q0 + bm;

    __shared__ __align__(16) float2 yu[NN];   // per-wave (y,u) broadcast
    float r0a[4], r1a[4];                     // results: cols 2c / 2c+1 per task

#define LOADT(DST, T)                                                          \
    { const float* Abt = Ab + (T) * (NN * NN);                                 \
      _Pragma("unroll")                                                        \
      for (int i = 0; i < 32; ++i)                                             \
          DST[i] = *reinterpret_cast<const float2*>(Abt + (2 * i + hi) * NN + 2 * c); }

#define TASK(CUR, JJ)                                                          \
    { yu[lane] = make_float2(xj[JJ], 1.0f);                                    \
      WAITLDS();                                                               \
      const float4 t01 = *reinterpret_cast<const float4*>(&yu[2 * c]);         \
      float a0 = fmaf(PpA[0], t01.x, c0f);                                     \
      float a1 = fmaf(PpA[0], t01.z, c0f);                                     \
      _Pragma("unroll")                                                        \
      for (int k = 1; k <= 3; ++k) {                                           \
          float ys0 = 0.f, ys1 = 0.f, us0 = 0.f, us1 = 0.f;                    \
          _Pragma("unroll")                                                    \
          for (int i = 0; i < 32; ++i) {                                       \
              const float2 t = yu[2 * i + hi];                                 \
              ys0 = fmaf(CUR[i].x, t.x, ys0);                                  \
              ys1 = fmaf(CUR[i].y, t.x, ys1);                                  \
              us0 = fmaf(CUR[i].x, t.y, us0);                                  \
              us1 = fmaf(CUR[i].y, t.y, us1);                                  \
          }                                                                    \
          ys0 += __shfl_xor(ys0, 32, 64);  ys1 += __shfl_xor(ys1, 32, 64);     \
          us0 += __shfl_xor(us0, 32, 64);  us1 += __shfl_xor(us1, 32, 64);     \
          ys0 *= OMB; ys1 *= OMB; us0 *= OMB; us1 *= OMB;                      \
          a0 = fmaf(PpA[k], ys0, fmaf(QA[k], us0, a0));                        \
          a1 = fmaf(PpA[k], ys1, fmaf(QA[k], us1, a1));                        \
          if (k < 3) {                                                         \
              if (hi == 0)                                                     \
                  *reinterpret_cast<float4*>(&yu[2 * c]) =                     \
                      make_float4(ys0, us0, ys1, us1);                         \
              WAITLDS();                                                       \
          }                                                                    \
      }                                                                        \
      r0a[JJ] = a0; r1a[JJ] = a1; }

    // 1-deep pipeline over the 4 s-values: prefetch tile j+1, compute tile j
    LOADT(avB, 1);  TASK(avA, 0);
    LOADT(avA, 2);  TASK(avB, 1);
    LOADT(avB, 3);  TASK(avA, 2);
                    TASK(avB, 3);

#undef LOADT
#undef TASK

    // lane (c,hi) stores row n = 2c+hi, float4 along s (16B-aligned)
    const int n = 2 * c + hi;
    float4 o;
    o.x = hi ? r1a[0] : r0a[0];
    o.y = hi ? r1a[1] : r0a[1];
    o.z = hi ? r1a[2] : r0a[2];
    o.w = hi ? r1a[3] : r0a[3];
    *reinterpret_cast<float4*>(&out[(size_t)(b * NN + n) * SS + s0]) = o;
}

extern "C" void kernel_launch(void* const* d_in, const int* in_sizes, int n_in,
                              void* d_out, int out_size, void* d_ws, size_t ws_size,
                              hipStream_t stream) {
    const float* x       = (const float*)d_in[0];
    const float* adj     = (const float*)d_in[1];
    const float* w_start = (const float*)d_in[2];
    const float* b_start = (const float*)d_in[3];
    const float* w_mlp   = (const float*)d_in[4];
    const float* b_mlp   = (const float*)d_in[5];
    float* out = (float*)d_out;

    const int grid = BB * (SS / 4);      // 2688 blocks x 64 thr (1 wave each)
    dgra_pipe2_kernel<<<grid, 64, 0, stream>>>(x, adj, w_start, b_start, w_mlp, b_mlp, out);
}

// Round 6
// 37.029 us; speedup vs baseline: 2.4575x; 1.1265x over previous
//
#include <hip/hip_runtime.h>

// DGraFormer graph-propagation, algebraically collapsed to 6 matvecs of
// A=adj[b,s,:,:] (64x64) per (b,s):
//   out[n] = sum_k P'_k y_k[n] + sum_k Q_k u_k[n] + (Q_0 + b_mlp)
//   y_k = (0.95 A^T)^k x[b,:,s],  u_k = (0.95 A^T)^k 1   (u1 = column sums).
// HBM/L3-bound: one pass over adj (176 MB).
//
// Round-6: round-3's proven shell (256 thr / 4 self-contained waves / one s
// per wave / no launch-bounds VGPR cap -- rounds 2,4,5 all showed forced
// register shapes spill or kill TLP). Two changes:
//  - A-tile via 16x global_load_dwordx4 (round-2 layout, 1 KB/instr):
//    lane (h=lane>>4, q=lane&15) holds av[i] = A[4i+h][4q..4q+3].
//  - k=1 matvec STREAMED in load order: consuming av[i] in issue order makes
//    the backend emit counted vmcnt(15..0) waits, so FMA starts when the
//    first line lands instead of after a vmcnt(0) drain. The register-only
//    MLP fold sits between issue and first use. u1 needs no multiplies
//    (t.y==1): pure adds.

#define BB 32
#define NN 64
#define SS 336
#define DD 32
#define BETA 0.05f
#define OMB 0.95f

#define WAITLDS() __asm__ volatile("s_waitcnt lgkmcnt(0)" ::: "memory")

__global__ __launch_bounds__(256) void dgra_stream_kernel(
    const float* __restrict__ x, const float* __restrict__ adj,
    const float* __restrict__ w_start, const float* __restrict__ b_start,
    const float* __restrict__ w_mlp, const float* __restrict__ b_mlp,
    float* __restrict__ out)
{
    const int tid  = threadIdx.x;
    const int lane = tid & 63;
    const int w    = tid >> 6;           // wave id = s within the s4 tile
    const int b    = blockIdx.x / (SS / 4);
    const int s4   = blockIdx.x % (SS / 4);
    const int s    = s4 * 4 + w;

    const int h = lane >> 4;             // row residue class (mod 4)
    const int q = lane & 15;             // column group: cols 4q..4q+3

    // ---- small loads FIRST (in-order vmcnt: their waits keep A in flight) ----
    const int  c2  = lane & 31;
    const int  hi2 = lane >> 5;
    const float wd  = w_start[c2];
    const float bd  = b_start[c2];
    const float m0f = w_mlp[(2 * hi2 + 0) * DD + c2];
    const float m1f = w_mlp[(2 * hi2 + 1) * DD + c2];
    const float bm  = b_mlp[0];
    const float xv  = x[(size_t)(b * NN + lane) * SS + s];

    __shared__ __align__(16) float2 yu[4][NN];   // per-wave (y,u) broadcast
    yu[w][lane] = make_float2(xv, 1.0f);         // drains vmcnt to 0 here (ok: A not issued yet)
    WAITLDS();

    // ---- issue the 16 A-tile loads (1 KB each, wave-contiguous) ----
    const float* Ab = adj + (size_t)(b * SS + s) * (NN * NN);
    float4 av[16];
#pragma unroll
    for (int i = 0; i < 16; ++i)
        av[i] = *reinterpret_cast<const float4*>(Ab + i * 256 + lane * 4);

    // ---- MLP fold: register-only shuffles, overlaps A-load latency ----
    float p0 = wd * m0f, q0 = bd * m0f, r0 = m0f;
    float p1 = wd * m1f, q1 = bd * m1f, r1 = m1f;
#pragma unroll
    for (int mask = 1; mask <= 16; mask <<= 1) {
        p0 += __shfl_xor(p0, mask, 64);  q0 += __shfl_xor(q0, mask, 64);  r0 += __shfl_xor(r0, mask, 64);
        p1 += __shfl_xor(p1, mask, 64);  q1 += __shfl_xor(q1, mask, 64);  r1 += __shfl_xor(r1, mask, 64);
    }
    const float po0 = __shfl_xor(p0, 32, 64), qo0 = __shfl_xor(q0, 32, 64), ro0 = __shfl_xor(r0, 32, 64);
    const float po1 = __shfl_xor(p1, 32, 64), qo1 = __shfl_xor(q1, 32, 64), ro1 = __shfl_xor(r1, 32, 64);
    const bool lo = (hi2 == 0);
    const float P0 = lo ? p0  : po0, P1 = lo ? p1  : po1, P2 = lo ? po0 : p0, P3 = lo ? po1 : p1;
    const float Q0 = lo ? q0  : qo0, Q1 = lo ? q1  : qo1, Q2 = lo ? qo0 : q0, Q3 = lo ? qo1 : q1;
    const float R1 = lo ? r1  : ro1, R2 = lo ? ro0 : r0,  R3 = lo ? ro1 : r1;
    const float PpA[4] = {P0 + BETA * (R1 + R2 + R3), P1 + BETA * (R2 + R3), P2 + BETA * R3, P3};
    const float QA[4]  = {Q0, Q1, Q2, Q3};
    const float c0f = Q0 + bm;

    // ---- k=1 matvec streamed in load order (per-use counted vmcnt waits) ----
    float ys0 = 0.f, ys1 = 0.f, ys2 = 0.f, ys3 = 0.f;
    float us0 = 0.f, us1 = 0.f, us2 = 0.f, us3 = 0.f;
#pragma unroll
    for (int i = 0; i < 16; ++i) {
        const float2 t = yu[w][4 * i + h];       // (x_{4i+h}, 1) broadcast
        ys0 = fmaf(av[i].x, t.x, ys0);  us0 += av[i].x;   // u1 = column sums
        ys1 = fmaf(av[i].y, t.x, ys1);  us1 += av[i].y;
        ys2 = fmaf(av[i].z, t.x, ys2);  us2 += av[i].z;
        ys3 = fmaf(av[i].w, t.x, ys3);  us3 += av[i].w;
    }
    ys0 += __shfl_xor(ys0, 16, 64);  ys0 += __shfl_xor(ys0, 32, 64);
    ys1 += __shfl_xor(ys1, 16, 64);  ys1 += __shfl_xor(ys1, 32, 64);
    ys2 += __shfl_xor(ys2, 16, 64);  ys2 += __shfl_xor(ys2, 32, 64);
    ys3 += __shfl_xor(ys3, 16, 64);  ys3 += __shfl_xor(ys3, 32, 64);
    us0 += __shfl_xor(us0, 16, 64);  us0 += __shfl_xor(us0, 32, 64);
    us1 += __shfl_xor(us1, 16, 64);  us1 += __shfl_xor(us1, 32, 64);
    us2 += __shfl_xor(us2, 16, 64);  us2 += __shfl_xor(us2, 32, 64);
    us3 += __shfl_xor(us3, 16, 64);  us3 += __shfl_xor(us3, 32, 64);
    ys0 *= OMB; ys1 *= OMB; ys2 *= OMB; ys3 *= OMB;
    us0 *= OMB; us1 *= OMB; us2 *= OMB; us3 *= OMB;

    // acc init from y0 (=x) at this lane's 4 columns, + k=1 contribution
    const float4 t01 = *reinterpret_cast<const float4*>(&yu[w][4 * q]);      // (x_{4q},1,x_{4q+1},1)
    const float4 t23 = *reinterpret_cast<const float4*>(&yu[w][4 * q + 2]);
    float acc0 = fmaf(PpA[0], t01.x, c0f);
    float acc1 = fmaf(PpA[0], t01.z, c0f);
    float acc2 = fmaf(PpA[0], t23.x, c0f);
    float acc3 = fmaf(PpA[0], t23.z, c0f);
    acc0 = fmaf(PpA[1], ys0, fmaf(QA[1], us0, acc0));
    acc1 = fmaf(PpA[1], ys1, fmaf(QA[1], us1, acc1));
    acc2 = fmaf(PpA[1], ys2, fmaf(QA[1], us2, acc2));
    acc3 = fmaf(PpA[1], ys3, fmaf(QA[1], us3, acc3));

    // handoff (y1,u1) for k=2
    if (h == 0) {
        *reinterpret_cast<float4*>(&yu[w][4 * q])     = make_float4(ys0, us0, ys1, us1);
        *reinterpret_cast<float4*>(&yu[w][4 * q + 2]) = make_float4(ys2, us2, ys3, us3);
    }
    WAITLDS();

    // ---- k = 2, 3 ----
#pragma unroll
    for (int k = 2; k <= 3; ++k) {
        ys0 = 0.f; ys1 = 0.f; ys2 = 0.f; ys3 = 0.f;
        us0 = 0.f; us1 = 0.f; us2 = 0.f; us3 = 0.f;
#pragma unroll
        for (int i = 0; i < 16; ++i) {
            const float2 t = yu[w][4 * i + h];
            ys0 = fmaf(av[i].x, t.x, ys0);  us0 = fmaf(av[i].x, t.y, us0);
            ys1 = fmaf(av[i].y, t.x, ys1);  us1 = fmaf(av[i].y, t.y, us1);
            ys2 = fmaf(av[i].z, t.x, ys2);  us2 = fmaf(av[i].z, t.y, us2);
            ys3 = fmaf(av[i].w, t.x, ys3);  us3 = fmaf(av[i].w, t.y, us3);
        }
        ys0 += __shfl_xor(ys0, 16, 64);  ys0 += __shfl_xor(ys0, 32, 64);
        ys1 += __shfl_xor(ys1, 16, 64);  ys1 += __shfl_xor(ys1, 32, 64);
        ys2 += __shfl_xor(ys2, 16, 64);  ys2 += __shfl_xor(ys2, 32, 64);
        ys3 += __shfl_xor(ys3, 16, 64);  ys3 += __shfl_xor(ys3, 32, 64);
        us0 += __shfl_xor(us0, 16, 64);  us0 += __shfl_xor(us0, 32, 64);
        us1 += __shfl_xor(us1, 16, 64);  us1 += __shfl_xor(us1, 32, 64);
        us2 += __shfl_xor(us2, 16, 64);  us2 += __shfl_xor(us2, 32, 64);
        us3 += __shfl_xor(us3, 16, 64);  us3 += __shfl_xor(us3, 32, 64);
        ys0 *= OMB; ys1 *= OMB; ys2 *= OMB; ys3 *= OMB;
        us0 *= OMB; us1 *= OMB; us2 *= OMB; us3 *= OMB;

        acc0 = fmaf(PpA[k], ys0, fmaf(QA[k], us0, acc0));
        acc1 = fmaf(PpA[k], ys1, fmaf(QA[k], us1, acc1));
        acc2 = fmaf(PpA[k], ys2, fmaf(QA[k], us2, acc2));
        acc3 = fmaf(PpA[k], ys3, fmaf(QA[k], us3, acc3));

        if (k < 3) {
            if (h == 0) {
                *reinterpret_cast<float4*>(&yu[w][4 * q])     = make_float4(ys0, us0, ys1, us1);
                *reinterpret_cast<float4*>(&yu[w][4 * q + 2]) = make_float4(ys2, us2, ys3, us3);
            }
            WAITLDS();
        }
    }

    // ---- transpose through LDS for float4-coalesced stores along s ----
    __shared__ __align__(16) float res[NN][4];
    if (h == 0) {
        res[4 * q + 0][w] = acc0;
        res[4 * q + 1][w] = acc1;
        res[4 * q + 2][w] = acc2;
        res[4 * q + 3][w] = acc3;
    }
    __syncthreads();
    if (w == 0) {
        const float4 v = *reinterpret_cast<const float4*>(res[lane]);
        *reinterpret_cast<float4*>(&out[(size_t)(b * NN + lane) * SS + s4 * 4]) = v;
    }
}

extern "C" void kernel_launch(void* const* d_in, const int* in_sizes, int n_in,
                              void* d_out, int out_size, void* d_ws, size_t ws_size,
                              hipStream_t stream) {
    const float* x       = (const float*)d_in[0];
    const float* adj     = (const float*)d_in[1];
    const float* w_start = (const float*)d_in[2];
    const float* b_start = (const float*)d_in[3];
    const float* w_mlp   = (const float*)d_in[4];
    const float* b_mlp   = (const float*)d_in[5];
    float* out = (float*)d_out;

    const int grid = BB * (SS / 4);      // 2688 blocks x 256 thr (4 waves)
    dgra_stream_kernel<<<grid, 256, 0, stream>>>(x, adj, w_start, b_start, w_mlp, b_mlp, out);
}

// Round 7
// 36.191 us; speedup vs baseline: 2.5144x; 1.0232x over previous
//
#include <hip/hip_runtime.h>

// DGraFormer graph-propagation block, algebraically collapsed to 6 matvecs
// of A=adj[b,s,:,:] (64x64) per (b,s):
//   out[n] = sum_k P'_k y_k[n] + sum_k Q_k u_k[n] + (Q_0 + b_mlp)
// with y_k = (0.95 A^T)^k x[b,:,s], u_k = (0.95 A^T)^k 1.
// Memory-bound: one streaming pass over adj (176 MB).
//
// FINAL (= round-3 kernel, best measured: 35.9 us = 5.07 TB/s read).
// Plateau evidence: rounds 1/3/6 (scalar, x2, x4 loads; streamed k1) all land
// 35.9-37.5 us; queueing arithmetic shows ~300 KB reads outstanding per CU vs
// ~9 KB needed -> memory system saturated; structure-insensitive = read-BW
// roofline. Forced-VGPR shapes (rounds 2,4) spill catastrophically; ILP-heavy
// 1-wave shape (round 5) loses TLP. This 4-wave/96-VGPR/~20-waves-per-CU
// shape is the measured optimum.

#define BB 32
#define NN 64
#define SS 336
#define DD 32
#define BETA 0.05f
#define OMB 0.95f

#define WAITLDS() __asm__ volatile("s_waitcnt lgkmcnt(0)" ::: "memory")

__global__ __launch_bounds__(256) void dgra_collapsed_kernel(
    const float* __restrict__ x, const float* __restrict__ adj,
    const float* __restrict__ w_start, const float* __restrict__ b_start,
    const float* __restrict__ w_mlp, const float* __restrict__ b_mlp,
    float* __restrict__ out)
{
    const int tid  = threadIdx.x;
    const int lane = tid & 63;
    const int w    = tid >> 6;           // wave id = s within the s4 tile
    const int blk  = blockIdx.x;
    const int b    = blk / (SS / 4);
    const int s4   = blk % (SS / 4);
    const int s    = s4 * 4 + w;

    const int c  = lane & 31;            // column pair: cols 2c, 2c+1
    const int hi = lane >> 5;            // row parity

    // ---- stage A: 32 x dwordx2; av[i] = { A[2i+hi][2c], A[2i+hi][2c+1] } ----
    const float* Ab = adj + (size_t)(b * SS + s) * (NN * NN);
    float2 av[32];
#pragma unroll
    for (int i = 0; i < 32; ++i)
        av[i] = *reinterpret_cast<const float2*>(Ab + (2 * i + hi) * NN + 2 * c);

    const float xv = x[(size_t)(b * NN + lane) * SS + s];

    // ---- lane-parallel MLP fold (overlaps load latency) ----
    // lane d = lane&31; half 0 handles k={0,1}, half 1 handles k={2,3}
    const float wd = w_start[c];
    const float bd = b_start[c];
    const float m0 = w_mlp[(2 * hi + 0) * DD + c];
    const float m1 = w_mlp[(2 * hi + 1) * DD + c];
    float p0 = wd * m0, q0 = bd * m0, r0 = m0;
    float p1 = wd * m1, q1 = bd * m1, r1 = m1;
#pragma unroll
    for (int mask = 1; mask <= 16; mask <<= 1) {
        p0 += __shfl_xor(p0, mask, 64);  q0 += __shfl_xor(q0, mask, 64);  r0 += __shfl_xor(r0, mask, 64);
        p1 += __shfl_xor(p1, mask, 64);  q1 += __shfl_xor(q1, mask, 64);  r1 += __shfl_xor(r1, mask, 64);
    }
    const float po0 = __shfl_xor(p0, 32, 64), qo0 = __shfl_xor(q0, 32, 64), ro0 = __shfl_xor(r0, 32, 64);
    const float po1 = __shfl_xor(p1, 32, 64), qo1 = __shfl_xor(q1, 32, 64), ro1 = __shfl_xor(r1, 32, 64);
    const bool lo = (hi == 0);
    const float P0 = lo ? p0  : po0, P1 = lo ? p1  : po1, P2 = lo ? po0 : p0, P3 = lo ? po1 : p1;
    const float Q0 = lo ? q0  : qo0, Q1 = lo ? q1  : qo1, Q2 = lo ? qo0 : q0, Q3 = lo ? qo1 : q1;
    const float R1 = lo ? r1  : ro1, R2 = lo ? ro0 : r0,  R3 = lo ? ro1 : r1;

    const float Pp0 = P0 + BETA * (R1 + R2 + R3);
    const float c0  = Q0 + b_mlp[0];
    const float PpA[4] = {Pp0, P1 + BETA * (R2 + R3), P2 + BETA * R3, P3};
    const float QA[4]  = {Q0, Q1, Q2, Q3};

    // ---- per-wave (y,u) broadcast buffer ----
    __shared__ __align__(16) float2 yu[4][NN];
    yu[w][lane] = make_float2(xv, 1.0f);
    WAITLDS();

    // acc init from y0 at this lane's 2 columns
    const float4 t01 = *reinterpret_cast<const float4*>(&yu[w][2 * c]);  // {y2c,1,y2c+1,1}
    float acc0 = fmaf(Pp0, t01.x, c0);
    float acc1 = fmaf(Pp0, t01.z, c0);

#pragma unroll
    for (int k = 1; k <= 3; ++k) {
        float ys0 = 0.f, ys1 = 0.f, us0 = 0.f, us1 = 0.f;
#pragma unroll
        for (int i = 0; i < 32; ++i) {
            const float2 t = yu[w][2 * i + hi];  // 2 distinct addrs -> broadcast
            ys0 = fmaf(av[i].x, t.x, ys0);
            ys1 = fmaf(av[i].y, t.x, ys1);
            us0 = fmaf(av[i].x, t.y, us0);
            us1 = fmaf(av[i].y, t.y, us1);
        }
        // combine the two row-parity partials
        ys0 += __shfl_xor(ys0, 32, 64);
        ys1 += __shfl_xor(ys1, 32, 64);
        us0 += __shfl_xor(us0, 32, 64);
        us1 += __shfl_xor(us1, 32, 64);
        ys0 *= OMB; ys1 *= OMB; us0 *= OMB; us1 *= OMB;

        acc0 = fmaf(PpA[k], ys0, fmaf(QA[k], us0, acc0));
        acc1 = fmaf(PpA[k], ys1, fmaf(QA[k], us1, acc1));

        if (k < 3) {
            if (hi == 0)
                *reinterpret_cast<float4*>(&yu[w][2 * c]) = make_float4(ys0, us0, ys1, us1);
            WAITLDS();
        }
    }

    // ---- transpose through LDS for float4-coalesced stores along s ----
    __shared__ __align__(16) float res[NN][4];
    if (hi == 0) {
        res[2 * c + 0][w] = acc0;
        res[2 * c + 1][w] = acc1;
    }
    __syncthreads();
    if (w == 0) {
        const float4 v = *reinterpret_cast<const float4*>(res[lane]);
        *reinterpret_cast<float4*>(&out[(size_t)(b * NN + lane) * SS + s4 * 4]) = v;
    }
}

extern "C" void kernel_launch(void* const* d_in, const int* in_sizes, int n_in,
                              void* d_out, int out_size, void* d_ws, size_t ws_size,
                              hipStream_t stream) {
    const float* x       = (const float*)d_in[0];
    const float* adj     = (const float*)d_in[1];
    const float* w_start = (const float*)d_in[2];
    const float* b_start = (const float*)d_in[3];
    const float* w_mlp   = (const float*)d_in[4];
    const float* b_mlp   = (const float*)d_in[5];
    float* out = (float*)d_out;

    const int grid = BB * (SS / 4);      // 32 * 84 = 2688 blocks, 4 waves each
    dgra_collapsed_kernel<<<grid, 256, 0, stream>>>(x, adj, w_start, b_start, w_mlp, b_mlp, out);
}